// Round 1
// baseline (848.968 us; speedup 1.0000x reference)
//
#include <hip/hip_runtime.h>
#include <math.h>

// ---------------- CSR build ----------------
__global__ void k_hist(const int* __restrict__ dst, int* __restrict__ deg, int E) {
    int e = blockIdx.x * 256 + threadIdx.x;
    if (e < E) atomicAdd(&deg[dst[e]], 1);
}

__global__ void k_scan1(const int* __restrict__ deg, int* __restrict__ rp,
                        int* __restrict__ bsum, int n) {
    __shared__ int sh[256];
    int t = threadIdx.x;
    int base = blockIdx.x * 1024 + t * 4;
    int v0 = (base + 0 < n) ? deg[base + 0] : 0;
    int v1 = (base + 1 < n) ? deg[base + 1] : 0;
    int v2 = (base + 2 < n) ? deg[base + 2] : 0;
    int v3 = (base + 3 < n) ? deg[base + 3] : 0;
    int ts = v0 + v1 + v2 + v3;
    sh[t] = ts;
    __syncthreads();
    for (int off = 1; off < 256; off <<= 1) {
        int x = (t >= off) ? sh[t - off] : 0;
        __syncthreads();
        sh[t] += x;
        __syncthreads();
    }
    int run = sh[t] - ts;  // exclusive prefix for this thread
    if (base + 0 < n) rp[base + 0] = run;
    run += v0;
    if (base + 1 < n) rp[base + 1] = run;
    run += v1;
    if (base + 2 < n) rp[base + 2] = run;
    run += v2;
    if (base + 3 < n) rp[base + 3] = run;
    if (t == 255) bsum[blockIdx.x] = sh[255];
}

__global__ void k_scan2(int* __restrict__ bsum, int nb) {
    __shared__ int sh[256];
    int t = threadIdx.x;
    int v = (t < nb) ? bsum[t] : 0;
    sh[t] = v;
    __syncthreads();
    for (int off = 1; off < 256; off <<= 1) {
        int x = (t >= off) ? sh[t - off] : 0;
        __syncthreads();
        sh[t] += x;
        __syncthreads();
    }
    if (t < nb) bsum[t] = sh[t] - v;  // exclusive
}

__global__ void k_scan3(int* __restrict__ rp, const int* __restrict__ bsum, int n, int total) {
    int t = threadIdx.x;
    int base = blockIdx.x * 1024 + t * 4;
    int add = bsum[blockIdx.x];
    if (base + 0 < n) rp[base + 0] += add;
    if (base + 1 < n) rp[base + 1] += add;
    if (base + 2 < n) rp[base + 2] += add;
    if (base + 3 < n) rp[base + 3] += add;
    if (blockIdx.x == 0 && t == 0) rp[n] = total;
}

__global__ void k_scatter(const int* __restrict__ src, const int* __restrict__ dst,
                          const int* __restrict__ rp, int* __restrict__ cur,
                          int* __restrict__ src_perm, int* __restrict__ eid_perm, int E) {
    int e = blockIdx.x * 256 + threadIdx.x;
    if (e < E) {
        int d = dst[e];
        int pos = rp[d] + atomicAdd(&cur[d], 1);
        src_perm[pos] = src[e];
        eid_perm[pos] = e;
    }
}

// ---------------- fused projections: Y{0..3} = X @ W{0..3} + b{0..3} ----------------
template <int FIN, int FOUT>
__global__ __launch_bounds__(320) void k_proj4(
    const float* __restrict__ X,
    const float* __restrict__ W0, const float* __restrict__ W1q,
    const float* __restrict__ W2q, const float* __restrict__ W3q,
    const float* __restrict__ b0, const float* __restrict__ b1q,
    const float* __restrict__ b2q, const float* __restrict__ b3q,
    float* __restrict__ Y0, float* __restrict__ Y1, float* __restrict__ Y2,
    float* __restrict__ Y3, int N) {
    constexpr int COLS = 4 * FOUT;      // 160 or 80
    constexpr int NG   = 320 / COLS;    // 2 or 4 node groups
    constexpr int NPB  = 32;            // nodes per block
    constexpr int NPT  = NPB / NG;      // 16 or 8 nodes per thread
    __shared__ float xs[NPB][FIN];
    int t  = threadIdx.x;
    int nb = blockIdx.x * NPB;
    for (int i = t; i < NPB * FIN; i += 320) {
        int node = nb + i / FIN;
        xs[i / FIN][i % FIN] = (node < N) ? X[(size_t)node * FIN + (i % FIN)] : 0.f;
    }
    __syncthreads();
    int col = t % COLS;
    int ng  = t / COLS;
    int which = col / FOUT, cc = col % FOUT;
    const float* W = (which == 0) ? W0 : (which == 1) ? W1q : (which == 2) ? W2q : W3q;
    const float* B = (which == 0) ? b0 : (which == 1) ? b1q : (which == 2) ? b2q : b3q;
    float* Y = (which == 0) ? Y0 : (which == 1) ? Y1 : (which == 2) ? Y2 : Y3;
    float bias = B[cc];
    float acc[NPT];
#pragma unroll
    for (int i = 0; i < NPT; ++i) acc[i] = bias;
    int nodebase = ng * NPT;
    for (int kk = 0; kk < FIN; ++kk) {
        float w = W[kk * FOUT + cc];
#pragma unroll
        for (int i = 0; i < NPT; ++i) acc[i] += xs[nodebase + i][kk] * w;
    }
#pragma unroll
    for (int i = 0; i < NPT; ++i) {
        int node = nb + nodebase + i;
        if (node < N) Y[(size_t)node * FOUT + cc] = acc[i];
    }
}

// ---------------- fused TransformerConv: one wave per dst node ----------------
// lane = slot(0..15)*4 + h(0..3). Online softmax per lane over its edge slots,
// then shfl_xor online-merge across the 16 slots. No atomics, no alpha buffer.
template <int CH>
__global__ __launch_bounds__(256) void k_conv(
    const int* __restrict__ rp, const int* __restrict__ src_perm,
    const int* __restrict__ eid_perm, const float* __restrict__ eattr,
    const float* __restrict__ We, const float* __restrict__ q,
    const float* __restrict__ k, const float* __restrict__ v,
    const float* __restrict__ skp, float* __restrict__ hout, float inv_sqrt, int N) {
    constexpr int D = 4 * CH;
    __shared__ float we_s[8 * D];
    for (int i = threadIdx.x; i < 8 * D; i += 256) we_s[i] = We[i];
    __syncthreads();
    int warp = threadIdx.x >> 6;
    int lane = threadIdx.x & 63;
    int dst  = blockIdx.x * 4 + warp;
    if (dst >= N) return;
    int slot = lane >> 2;
    int h    = lane & 3;
    int rs = rp[dst], re = rp[dst + 1];
    float qh[CH];
#pragma unroll
    for (int c = 0; c < CH; ++c) qh[c] = q[(size_t)dst * D + h * CH + c];
    float m = -3.0e38f, l = 0.f;
    float acc[CH] = {};
    for (int p = rs + slot; p < re; p += 16) {
        int sidx = src_perm[p];
        int eid  = eid_perm[p];
        const float4* eap = (const float4*)(eattr + (size_t)eid * 8);
        float4 e0 = eap[0], e1 = eap[1];
        float ea8[8] = {e0.x, e0.y, e0.z, e0.w, e1.x, e1.y, e1.z, e1.w};
        float ej[CH];
#pragma unroll
        for (int c = 0; c < CH; ++c) {
            float sE = 0.f;
#pragma unroll
            for (int j = 0; j < 8; ++j) sE += ea8[j] * we_s[j * D + h * CH + c];
            ej[c] = sE;
        }
        const float* kr = k + (size_t)sidx * D + h * CH;
        const float* vr = v + (size_t)sidx * D + h * CH;
        float a = 0.f;
        float vj[CH];
#pragma unroll
        for (int c = 0; c < CH; ++c) {
            a += qh[c] * (kr[c] + ej[c]);
            vj[c] = vr[c] + ej[c];
        }
        a *= inv_sqrt;
        float mn = fmaxf(m, a);
        float so = expf(m - mn);   // first iter: exp(-3e38) == 0
        float w  = expf(a - mn);
        l = l * so + w;
#pragma unroll
        for (int c = 0; c < CH; ++c) acc[c] = acc[c] * so + w * vj[c];
        m = mn;
    }
    // merge the 16 slots of each head (lanes with same lane&3)
#pragma unroll
    for (int mask = 4; mask <= 32; mask <<= 1) {
        float mo = __shfl_xor(m, mask);
        float lo = __shfl_xor(l, mask);
        float mn = fmaxf(m, mo);
        float s1 = (m  > -1e37f) ? expf(m  - mn) : 0.f;
        float s2 = (mo > -1e37f) ? expf(mo - mn) : 0.f;
        l = l * s1 + lo * s2;
#pragma unroll
        for (int c = 0; c < CH; ++c) {
            float ao = __shfl_xor(acc[c], mask);
            acc[c] = acc[c] * s1 + ao * s2;
        }
        m = mn;
    }
    if (slot == 0) {
        float inv = 1.0f / (l + 1e-16f);
#pragma unroll
        for (int c = 0; c < CH; ++c) {
            float o = acc[c] * inv + skp[(size_t)dst * D + h * CH + c];
            hout[(size_t)dst * D + h * CH + c] = fmaxf(o, 0.f);
        }
    }
}

// ---------------- pooling (batch is sorted) ----------------
__global__ void k_pool(const float* __restrict__ h2, const int* __restrict__ batch,
                       float* __restrict__ pooled, float* __restrict__ cnt, int N) {
    int t = blockIdx.x * 256 + threadIdx.x;
    int start = t * 16;
    if (start >= N) return;
    int end = min(start + 16, N);
    float acc[20];
#pragma unroll
    for (int c = 0; c < 20; ++c) acc[c] = 0.f;
    int cg = batch[start];
    float run = 0.f;
    for (int n = start; n < end; ++n) {
        int g = batch[n];
        if (g != cg) {
#pragma unroll
            for (int c = 0; c < 20; ++c) atomicAdd(&pooled[cg * 20 + c], acc[c]);
            atomicAdd(&cnt[cg], run);
#pragma unroll
            for (int c = 0; c < 20; ++c) acc[c] = 0.f;
            run = 0.f;
            cg = g;
        }
#pragma unroll
        for (int c = 0; c < 20; ++c) acc[c] += h2[(size_t)n * 20 + c];
        run += 1.f;
    }
#pragma unroll
    for (int c = 0; c < 20; ++c) atomicAdd(&pooled[cg * 20 + c], acc[c]);
    atomicAdd(&cnt[cg], run);
}

__global__ void k_mlp(const float* __restrict__ pooled, const float* __restrict__ cnt,
                      const float* __restrict__ W1, const float* __restrict__ b1,
                      const float* __restrict__ W2, const float* __restrict__ b2,
                      float* __restrict__ out) {
    int g = threadIdx.x;
    if (g >= 64) return;
    float ic = 1.0f / fmaxf(cnt[g], 1.0f);
    float p[20];
#pragma unroll
    for (int i = 0; i < 20; ++i) p[i] = pooled[g * 20 + i] * ic;
    float hid[10];
#pragma unroll
    for (int j = 0; j < 10; ++j) {
        float a = b1[j];
#pragma unroll
        for (int i = 0; i < 20; ++i) a += p[i] * W1[i * 10 + j];
        hid[j] = fmaxf(a, 0.f);
    }
#pragma unroll
    for (int o = 0; o < 3; ++o) {
        float a = b2[o];
#pragma unroll
        for (int j = 0; j < 10; ++j) a += hid[j] * W2[j * 3 + o];
        out[g * 3 + o] = a;
    }
}

extern "C" void kernel_launch(void* const* d_in, const int* in_sizes, int n_in,
                              void* d_out, int out_size, void* d_ws, size_t ws_size,
                              hipStream_t stream) {
    const float* x   = (const float*)d_in[0];
    const int* ei    = (const int*)d_in[1];
    const float* ea  = (const float*)d_in[2];
    const int* batch = (const int*)d_in[3];
    const float *Wq1 = (const float*)d_in[4],  *bq1 = (const float*)d_in[5];
    const float *Wk1 = (const float*)d_in[6],  *bk1 = (const float*)d_in[7];
    const float *Wv1 = (const float*)d_in[8],  *bv1 = (const float*)d_in[9];
    const float *We1 = (const float*)d_in[10];
    const float *Ws1 = (const float*)d_in[11], *bs1 = (const float*)d_in[12];
    const float *Wq2 = (const float*)d_in[13], *bq2 = (const float*)d_in[14];
    const float *Wk2 = (const float*)d_in[15], *bk2 = (const float*)d_in[16];
    const float *Wv2 = (const float*)d_in[17], *bv2 = (const float*)d_in[18];
    const float *We2 = (const float*)d_in[19];
    const float *Ws2 = (const float*)d_in[20], *bs2 = (const float*)d_in[21];
    const float *W1  = (const float*)d_in[22], *b1  = (const float*)d_in[23];
    const float *W2  = (const float*)d_in[24], *b2  = (const float*)d_in[25];

    const int N = in_sizes[0] / 128;  // 100000
    const int E = in_sizes[1] / 2;    // 1600000
    const int* srcI = ei;
    const int* dstI = ei + E;

    // workspace layout (floats)
    float* F = (float*)d_ws;
    float* q  = F;               // 4,000,000  (layer2 reuses first 2M)
    float* k  = F + 4000000;
    float* v  = F + 8000000;
    float* s  = F + 12000000;
    float* h1 = F + 16000000;    // 4,000,000
    float* h2 = F + 20000000;    // 2,000,000
    float* pooled = F + 22000000;  // 1280
    float* cnt    = F + 22001280;  // 64
    int* I   = (int*)(F + 22002048);
    int* deg = I;                 // N
    int* rpR = I + 100352;        // N+1
    int* cur = I + 200704;        // N
    int* bsum = I + 301056;       // <=256
    int* src_perm = I + 301312;   // E
    int* eid_perm = I + 1901312;  // E

    const int SCAN_BLOCKS = (N + 1023) / 1024;  // 98
    const int EB = (E + 255) / 256;             // 6250

    // zero counters
    hipMemsetAsync(deg, 0, (size_t)N * 4, stream);
    hipMemsetAsync(cur, 0, (size_t)N * 4, stream);
    hipMemsetAsync(pooled, 0, (1280 + 64) * 4, stream);

    // CSR build (shared by both layers)
    k_hist<<<EB, 256, 0, stream>>>(dstI, deg, E);
    k_scan1<<<SCAN_BLOCKS, 256, 0, stream>>>(deg, rpR, bsum, N);
    k_scan2<<<1, 256, 0, stream>>>(bsum, SCAN_BLOCKS);
    k_scan3<<<SCAN_BLOCKS, 256, 0, stream>>>(rpR, bsum, N, E);
    k_scatter<<<EB, 256, 0, stream>>>(srcI, dstI, rpR, cur, src_perm, eid_perm, E);

    // layer 1: 128 -> 4 heads x 10
    k_proj4<128, 40><<<(N + 31) / 32, 320, 0, stream>>>(
        x, Wq1, Wk1, Wv1, Ws1, bq1, bk1, bv1, bs1, q, k, v, s, N);
    k_conv<10><<<(N + 3) / 4, 256, 0, stream>>>(
        rpR, src_perm, eid_perm, ea, We1, q, k, v, s, h1, 0.31622776601683794f, N);

    // layer 2: 40 -> 4 heads x 5
    k_proj4<40, 20><<<(N + 31) / 32, 320, 0, stream>>>(
        h1, Wq2, Wk2, Wv2, Ws2, bq2, bk2, bv2, bs2, q, k, v, s, N);
    k_conv<5><<<(N + 3) / 4, 256, 0, stream>>>(
        rpR, src_perm, eid_perm, ea, We2, q, k, v, s, h2, 0.4472135954999579f, N);

    // pool + MLP
    k_pool<<<((N + 15) / 16 + 255) / 256, 256, 0, stream>>>(h2, batch, pooled, cnt, N);
    k_mlp<<<1, 64, 0, stream>>>(pooled, cnt, W1, b1, W2, b2, (float*)d_out);
}

// Round 2
// 628.327 us; speedup vs baseline: 1.3512x; 1.3512x over previous
//
#include <hip/hip_runtime.h>
#include <math.h>

// ---------- bf16 pack/unpack helpers (k in low16, v in high16) ----------
__device__ __forceinline__ unsigned bfr_(float f) {
    unsigned u = __float_as_uint(f);
    return (u + 0x7fffu + ((u >> 16) & 1u)) >> 16;
}
__device__ __forceinline__ unsigned pack2_(float lo, float hi) {
    return bfr_(lo) | (bfr_(hi) << 16);
}
__device__ __forceinline__ float unlo_(unsigned u) { return __uint_as_float(u << 16); }
__device__ __forceinline__ float unhi_(unsigned u) { return __uint_as_float(u & 0xffff0000u); }

// ---------------- CSR build ----------------
__global__ void k_hist(const int* __restrict__ dst, int* __restrict__ deg, int E) {
    int e = blockIdx.x * 256 + threadIdx.x;
    if (e < E) atomicAdd(&deg[dst[e]], 1);
}

__global__ void k_scan1(const int* __restrict__ deg, int* __restrict__ rp,
                        int* __restrict__ bsum, int n) {
    __shared__ int sh[256];
    int t = threadIdx.x;
    int base = blockIdx.x * 1024 + t * 4;
    int v0 = (base + 0 < n) ? deg[base + 0] : 0;
    int v1 = (base + 1 < n) ? deg[base + 1] : 0;
    int v2 = (base + 2 < n) ? deg[base + 2] : 0;
    int v3 = (base + 3 < n) ? deg[base + 3] : 0;
    int ts = v0 + v1 + v2 + v3;
    sh[t] = ts;
    __syncthreads();
    for (int off = 1; off < 256; off <<= 1) {
        int x = (t >= off) ? sh[t - off] : 0;
        __syncthreads();
        sh[t] += x;
        __syncthreads();
    }
    int run = sh[t] - ts;
    if (base + 0 < n) rp[base + 0] = run;
    run += v0;
    if (base + 1 < n) rp[base + 1] = run;
    run += v1;
    if (base + 2 < n) rp[base + 2] = run;
    run += v2;
    if (base + 3 < n) rp[base + 3] = run;
    if (t == 255) bsum[blockIdx.x] = sh[255];
}

__global__ void k_scan2(int* __restrict__ bsum, int nb) {
    __shared__ int sh[256];
    int t = threadIdx.x;
    int v = (t < nb) ? bsum[t] : 0;
    sh[t] = v;
    __syncthreads();
    for (int off = 1; off < 256; off <<= 1) {
        int x = (t >= off) ? sh[t - off] : 0;
        __syncthreads();
        sh[t] += x;
        __syncthreads();
    }
    if (t < nb) bsum[t] = sh[t] - v;
}

__global__ void k_scan3(int* __restrict__ rp, const int* __restrict__ bsum, int n, int total) {
    int t = threadIdx.x;
    int base = blockIdx.x * 1024 + t * 4;
    int add = bsum[blockIdx.x];
    if (base + 0 < n) rp[base + 0] += add;
    if (base + 1 < n) rp[base + 1] += add;
    if (base + 2 < n) rp[base + 2] += add;
    if (base + 3 < n) rp[base + 3] += add;
    if (blockIdx.x == 0 && t == 0) rp[n] = total;
}

// scatter: build src_perm + bf16-packed edge_attr in CSR (dst-sorted) order
__global__ void k_scatter(const int* __restrict__ src, const int* __restrict__ dst,
                          const int* __restrict__ rp, int* __restrict__ cur,
                          const float4* __restrict__ ea, int* __restrict__ src_perm,
                          uint4* __restrict__ eap, int E) {
    int e = blockIdx.x * 256 + threadIdx.x;
    if (e >= E) return;
    int d = dst[e];
    int pos = rp[d] + atomicAdd(&cur[d], 1);
    src_perm[pos] = src[e];
    float4 a = ea[(size_t)e * 2 + 0];
    float4 b = ea[(size_t)e * 2 + 1];
    uint4 u;
    u.x = pack2_(a.x, a.y);
    u.y = pack2_(a.z, a.w);
    u.z = pack2_(b.x, b.y);
    u.w = pack2_(b.z, b.w);
    eap[pos] = u;
}

// ---------------- projections: q,s f32; k,v packed bf16 into kv ----------------
// block: 64 nodes x (4*FOUT) cols; 256 threads = NCG col-groups(10) x NG node-groups(NPT)
template <int FIN, int FOUT, int KTILE, int NPT>
__global__ __launch_bounds__(256) void k_proj(
    const float* __restrict__ X,
    const float* __restrict__ Wq, const float* __restrict__ Wk,
    const float* __restrict__ Wv, const float* __restrict__ Ws,
    const float* __restrict__ bq, const float* __restrict__ bk,
    const float* __restrict__ bv, const float* __restrict__ bs,
    float* __restrict__ qO, unsigned* __restrict__ kvO, float* __restrict__ sO, int N) {
    constexpr int NPB = 64;
    constexpr int COLS = 4 * FOUT;
    constexpr int NCG = COLS / 10;
    constexpr int NG = 256 / NCG;
    static_assert(NG * NPT == NPB, "geometry");
    constexpr int F4 = FIN / 4;
    __shared__ float xs[FIN * NPB];       // transposed: xs[kk*64 + node]
    __shared__ float wbuf[KTILE * COLS];  // reused as kbuf[NPB][FOUT] in epilogue
    int t = threadIdx.x;
    int nb = blockIdx.x * NPB;
    // stage X transposed: lane-fastest over nodes -> conflict-free LDS writes
    for (int i = t; i < NPB * F4; i += 256) {
        int nl = i & 63;
        int k4 = (i >> 6) * 4;
        int node = nb + nl;
        float4 val = make_float4(0.f, 0.f, 0.f, 0.f);
        if (node < N) val = *(const float4*)(X + (size_t)node * FIN + k4);
        xs[(k4 + 0) * NPB + nl] = val.x;
        xs[(k4 + 1) * NPB + nl] = val.y;
        xs[(k4 + 2) * NPB + nl] = val.z;
        xs[(k4 + 3) * NPB + nl] = val.w;
    }
    int cg = t % NCG, ng = t / NCG;
    int which = (cg * 10) / FOUT, cc0 = (cg * 10) % FOUT;
    float acc[NPT][10];
#pragma unroll
    for (int i = 0; i < NPT; ++i)
#pragma unroll
        for (int j = 0; j < 10; ++j) acc[i][j] = 0.f;

    for (int kt = 0; kt < FIN; kt += KTILE) {
        __syncthreads();
        // stage W chunk [KTILE][COLS]
        for (int i = t; i < KTILE * (COLS / 4); i += 256) {
            int kk = i / (COLS / 4);
            int c4 = (i % (COLS / 4)) * 4;
            int wh = c4 / FOUT, cc = c4 % FOUT;
            const float* Wsrc = wh == 0 ? Wq : wh == 1 ? Wk : wh == 2 ? Wv : Ws;
            float4 wv = *(const float4*)(Wsrc + (size_t)(kt + kk) * FOUT + cc);
            wbuf[kk * COLS + c4 + 0] = wv.x;
            wbuf[kk * COLS + c4 + 1] = wv.y;
            wbuf[kk * COLS + c4 + 2] = wv.z;
            wbuf[kk * COLS + c4 + 3] = wv.w;
        }
        __syncthreads();
#pragma unroll 4
        for (int kk = 0; kk < KTILE; ++kk) {
            float xv[NPT];
            if constexpr (NPT == 4) {
                float4 x4 = *(const float4*)(xs + (kt + kk) * NPB + ng * 4);
                xv[0] = x4.x; xv[1] = x4.y; xv[2] = x4.z; xv[3] = x4.w;
            } else {
                float2 x2 = *(const float2*)(xs + (kt + kk) * NPB + ng * 2);
                xv[0] = x2.x; xv[1] = x2.y;
            }
            const float2* wp = (const float2*)(wbuf + kk * COLS + cg * 10);
            float wv[10];
#pragma unroll
            for (int jj = 0; jj < 5; ++jj) {
                float2 w2 = wp[jj];
                wv[2 * jj] = w2.x;
                wv[2 * jj + 1] = w2.y;
            }
#pragma unroll
            for (int i = 0; i < NPT; ++i)
#pragma unroll
                for (int j = 0; j < 10; ++j) acc[i][j] += xv[i] * wv[j];
        }
    }
    const float* B = which == 0 ? bq : which == 1 ? bk : which == 2 ? bv : bs;
    float bias[10];
#pragma unroll
    for (int j = 0; j < 10; ++j) bias[j] = B[cc0 + j];
    __syncthreads();  // done reading wbuf; reuse as kbuf
    if (which == 0 || which == 3) {
        float* Y = (which == 0) ? qO : sO;
#pragma unroll
        for (int i = 0; i < NPT; ++i) {
            int node = nb + ng * NPT + i;
            if (node < N)
#pragma unroll
                for (int j = 0; j < 10; ++j)
                    Y[(size_t)node * FOUT + cc0 + j] = acc[i][j] + bias[j];
        }
    } else if (which == 1) {  // k -> kbuf
#pragma unroll
        for (int i = 0; i < NPT; ++i) {
            int nl = ng * NPT + i;
#pragma unroll
            for (int j = 0; j < 10; ++j) wbuf[nl * FOUT + cc0 + j] = acc[i][j] + bias[j];
        }
    }
    __syncthreads();
    if (which == 2) {  // v: pack with matching k
#pragma unroll
        for (int i = 0; i < NPT; ++i) {
            int nl = ng * NPT + i;
            int node = nb + nl;
            if (node < N)
#pragma unroll
                for (int j = 0; j < 10; ++j) {
                    float kf = wbuf[nl * FOUT + cc0 + j];
                    kvO[(size_t)node * FOUT + cc0 + j] = pack2_(kf, acc[i][j] + bias[j]);
                }
        }
    }
}

// ---------------- fused TransformerConv: one wave per dst node ----------------
// lane = slot(0..15)*4 + h(0..3); edge transform factored out:
//   alpha = q.k + (We_h^T q).ea ; out = (sum w*v + We^T sum w*ea)/l + skip
template <int CH>
__global__ __launch_bounds__(256) void k_conv(
    const int* __restrict__ rp, const int* __restrict__ src_perm,
    const uint4* __restrict__ eap, const float* __restrict__ We,
    const float* __restrict__ q, const unsigned* __restrict__ kv,
    const float* __restrict__ skp, float* __restrict__ hout, float inv_sqrt, int N) {
    constexpr int D = 4 * CH;
    __shared__ float we_s[8 * D];
    for (int i = threadIdx.x; i < 8 * D; i += 256) we_s[i] = We[i];
    __syncthreads();
    int warp = threadIdx.x >> 6;
    int lane = threadIdx.x & 63;
    int dst = blockIdx.x * 4 + warp;
    if (dst >= N) return;
    int slot = lane >> 2;
    int h = lane & 3;
    int rs = rp[dst], re = rp[dst + 1];
    float qh[CH];
#pragma unroll
    for (int c = 0; c < CH; ++c) qh[c] = q[(size_t)dst * D + h * CH + c];
    float qe[8];
#pragma unroll
    for (int j = 0; j < 8; ++j) {
        float sE = 0.f;
#pragma unroll
        for (int c = 0; c < CH; ++c) sE += qh[c] * we_s[j * D + h * CH + c];
        qe[j] = sE;
    }
    float m = -3.0e38f, l = 0.f;
    float accv[CH] = {};
    float acce[8] = {};
    for (int p = rs + slot; p < re; p += 16) {
        int sidx = src_perm[p];
        uint4 eu = eap[p];
        float ea8[8];
        ea8[0] = unlo_(eu.x); ea8[1] = unhi_(eu.x);
        ea8[2] = unlo_(eu.y); ea8[3] = unhi_(eu.y);
        ea8[4] = unlo_(eu.z); ea8[5] = unhi_(eu.z);
        ea8[6] = unlo_(eu.w); ea8[7] = unhi_(eu.w);
        const unsigned* kr = kv + (size_t)sidx * D + h * CH;
        float a = 0.f;
        float vj[CH];
#pragma unroll
        for (int c = 0; c < CH; ++c) {
            unsigned u = kr[c];
            a += qh[c] * unlo_(u);
            vj[c] = unhi_(u);
        }
#pragma unroll
        for (int j = 0; j < 8; ++j) a += qe[j] * ea8[j];
        a *= inv_sqrt;
        float mn = fmaxf(m, a);
        float so = __expf(m - mn);
        float w = __expf(a - mn);
        l = l * so + w;
#pragma unroll
        for (int c = 0; c < CH; ++c) accv[c] = accv[c] * so + w * vj[c];
#pragma unroll
        for (int j = 0; j < 8; ++j) acce[j] = acce[j] * so + w * ea8[j];
        m = mn;
    }
    // merge the 16 slots of each head
#pragma unroll
    for (int mask = 4; mask <= 32; mask <<= 1) {
        float mo = __shfl_xor(m, mask);
        float lo = __shfl_xor(l, mask);
        float mn = fmaxf(m, mo);
        float s1 = (m > -1e37f) ? __expf(m - mn) : 0.f;
        float s2 = (mo > -1e37f) ? __expf(mo - mn) : 0.f;
        l = l * s1 + lo * s2;
#pragma unroll
        for (int c = 0; c < CH; ++c) {
            float ao = __shfl_xor(accv[c], mask);
            accv[c] = accv[c] * s1 + ao * s2;
        }
#pragma unroll
        for (int j = 0; j < 8; ++j) {
            float ao = __shfl_xor(acce[j], mask);
            acce[j] = acce[j] * s1 + ao * s2;
        }
        m = mn;
    }
    if (slot == 0) {
        float inv = 1.0f / (l + 1e-16f);
#pragma unroll
        for (int c = 0; c < CH; ++c) {
            float ec = 0.f;
#pragma unroll
            for (int j = 0; j < 8; ++j) ec += acce[j] * we_s[j * D + h * CH + c];
            float o = (accv[c] + ec) * inv + skp[(size_t)dst * D + h * CH + c];
            hout[(size_t)dst * D + h * CH + c] = fmaxf(o, 0.f);
        }
    }
}

// ---------------- pooling (batch is sorted) ----------------
__global__ void k_pool(const float* __restrict__ h2, const int* __restrict__ batch,
                       float* __restrict__ pooled, float* __restrict__ cnt, int N) {
    int t = blockIdx.x * 256 + threadIdx.x;
    int start = t * 16;
    if (start >= N) return;
    int end = min(start + 16, N);
    float acc[20];
#pragma unroll
    for (int c = 0; c < 20; ++c) acc[c] = 0.f;
    int cg = batch[start];
    float run = 0.f;
    for (int n = start; n < end; ++n) {
        int g = batch[n];
        if (g != cg) {
#pragma unroll
            for (int c = 0; c < 20; ++c) atomicAdd(&pooled[cg * 20 + c], acc[c]);
            atomicAdd(&cnt[cg], run);
#pragma unroll
            for (int c = 0; c < 20; ++c) acc[c] = 0.f;
            run = 0.f;
            cg = g;
        }
#pragma unroll
        for (int c = 0; c < 20; ++c) acc[c] += h2[(size_t)n * 20 + c];
        run += 1.f;
    }
#pragma unroll
    for (int c = 0; c < 20; ++c) atomicAdd(&pooled[cg * 20 + c], acc[c]);
    atomicAdd(&cnt[cg], run);
}

__global__ void k_mlp(const float* __restrict__ pooled, const float* __restrict__ cnt,
                      const float* __restrict__ W1, const float* __restrict__ b1,
                      const float* __restrict__ W2, const float* __restrict__ b2,
                      float* __restrict__ out) {
    int g = threadIdx.x;
    if (g >= 64) return;
    float ic = 1.0f / fmaxf(cnt[g], 1.0f);
    float p[20];
#pragma unroll
    for (int i = 0; i < 20; ++i) p[i] = pooled[g * 20 + i] * ic;
    float hid[10];
#pragma unroll
    for (int j = 0; j < 10; ++j) {
        float a = b1[j];
#pragma unroll
        for (int i = 0; i < 20; ++i) a += p[i] * W1[i * 10 + j];
        hid[j] = fmaxf(a, 0.f);
    }
#pragma unroll
    for (int o = 0; o < 3; ++o) {
        float a = b2[o];
#pragma unroll
        for (int j = 0; j < 10; ++j) a += hid[j] * W2[j * 3 + o];
        out[g * 3 + o] = a;
    }
}

extern "C" void kernel_launch(void* const* d_in, const int* in_sizes, int n_in,
                              void* d_out, int out_size, void* d_ws, size_t ws_size,
                              hipStream_t stream) {
    const float* x   = (const float*)d_in[0];
    const int* ei    = (const int*)d_in[1];
    const float* ea  = (const float*)d_in[2];
    const int* batch = (const int*)d_in[3];
    const float *Wq1 = (const float*)d_in[4],  *bq1 = (const float*)d_in[5];
    const float *Wk1 = (const float*)d_in[6],  *bk1 = (const float*)d_in[7];
    const float *Wv1 = (const float*)d_in[8],  *bv1 = (const float*)d_in[9];
    const float *We1 = (const float*)d_in[10];
    const float *Ws1 = (const float*)d_in[11], *bs1 = (const float*)d_in[12];
    const float *Wq2 = (const float*)d_in[13], *bq2 = (const float*)d_in[14];
    const float *Wk2 = (const float*)d_in[15], *bk2 = (const float*)d_in[16];
    const float *Wv2 = (const float*)d_in[17], *bv2 = (const float*)d_in[18];
    const float *We2 = (const float*)d_in[19];
    const float *Ws2 = (const float*)d_in[20], *bs2 = (const float*)d_in[21];
    const float *W1  = (const float*)d_in[22], *b1  = (const float*)d_in[23];
    const float *W2  = (const float*)d_in[24], *b2  = (const float*)d_in[25];

    const int N = in_sizes[0] / 128;  // 100000
    const int E = in_sizes[1] / 2;    // 1600000
    const int* srcI = ei;
    const int* dstI = ei + E;

    // workspace layout (4B units), total ~97.2 MB
    float* F = (float*)d_ws;
    float*    q      = F;                       // 4,000,000
    float*    s      = F + 4000000;             // 4,000,000
    unsigned* kv     = (unsigned*)(F + 8000000);  // 4,000,000 (layer2 uses [0,2M))
    float*    h2     = F + 8000000 + 2000000;   // 2,000,000 (aliases kv[2M..4M) - dead by then)
    float*    h1     = F + 12000000;            // 4,000,000
    float*    pooled = F + 16000000;            // 1280
    float*    cnt    = F + 16001280;            // 64
    int* I = (int*)(F + 16002048);
    int* deg  = I;                // 100,352
    int* rpR  = I + 100352;       // 100,352 (N+1)
    int* cur  = I + 200704;       // 100,352
    int* bsum = I + 301056;       // 256
    int* src_perm = I + 301312;   // 1,600,000
    uint4* eap = (uint4*)(I + 1901312);  // 6,400,000 units, 16B-aligned

    const int SCAN_BLOCKS = (N + 1023) / 1024;
    const int EB = (E + 255) / 256;

    hipMemsetAsync(deg, 0, (size_t)N * 4, stream);
    hipMemsetAsync(cur, 0, (size_t)N * 4, stream);
    hipMemsetAsync(pooled, 0, (1280 + 64) * 4, stream);

    // CSR build (shared by both layers) + bf16 edge_attr permute
    k_hist<<<EB, 256, 0, stream>>>(dstI, deg, E);
    k_scan1<<<SCAN_BLOCKS, 256, 0, stream>>>(deg, rpR, bsum, N);
    k_scan2<<<1, 256, 0, stream>>>(bsum, SCAN_BLOCKS);
    k_scan3<<<SCAN_BLOCKS, 256, 0, stream>>>(rpR, bsum, N, E);
    k_scatter<<<EB, 256, 0, stream>>>(srcI, dstI, rpR, cur, (const float4*)ea,
                                      src_perm, eap, E);

    // layer 1: 128 -> 4 heads x 10
    k_proj<128, 40, 32, 4><<<(N + 63) / 64, 256, 0, stream>>>(
        x, Wq1, Wk1, Wv1, Ws1, bq1, bk1, bv1, bs1, q, kv, s, N);
    k_conv<10><<<(N + 3) / 4, 256, 0, stream>>>(
        rpR, src_perm, eap, We1, q, kv, s, h1, 0.31622776601683794f, N);

    // layer 2: 40 -> 4 heads x 5
    k_proj<40, 20, 40, 2><<<(N + 63) / 64, 256, 0, stream>>>(
        h1, Wq2, Wk2, Wv2, Ws2, bq2, bk2, bv2, bs2, q, kv, s, N);
    k_conv<5><<<(N + 3) / 4, 256, 0, stream>>>(
        rpR, src_perm, eap, We2, q, kv, s, h2, 0.4472135954999579f, N);

    // pool + MLP
    k_pool<<<((N + 15) / 16 + 255) / 256, 256, 0, stream>>>(h2, batch, pooled, cnt, N);
    k_mlp<<<1, 64, 0, stream>>>(pooled, cnt, W1, b1, W2, b2, (float*)d_out);
}